// Round 7
// baseline (77888.367 us; speedup 1.0000x reference)
//
#include <hip/hip_runtime.h>
#include <stdint.h>

#define T_   256
#define V_   10000
#define SOS_ 1

typedef unsigned long long u64;
typedef unsigned int u32;
typedef unsigned short u16;
typedef _Float16 h8 __attribute__((ext_vector_type(8)));
typedef float f32x4 __attribute__((ext_vector_type(4)));

__device__ __forceinline__ float sig_(float v){ return 1.f/(1.f+__expf(-v)); }

__device__ __forceinline__ u16 h2u(_Float16 h){ union{ _Float16 h; u16 u; } x; x.h=h; return x.u; }

// split f32 -> fp16 hi + fp16 lo*2^11 (lo pre-scaled so it stays normal)
__device__ __forceinline__ void cvt8(const float* v, h8& hi, h8& lo){
#pragma unroll
  for(int j=0;j<8;++j){
    _Float16 h = (_Float16)v[j];
    hi[j] = h;
    lo[j] = (_Float16)((v[j] - (float)h) * 2048.f);
  }
}

// 3-pass split-fp16 MFMA: a0 += Ahi*Whi ; ax += Alo2k*Whi + Ahi*Wlo2k
__device__ __forceinline__ void mm3(h8 ah, h8 al, h8 wh, h8 wl, f32x4& a0, f32x4& ax){
  a0 = __builtin_amdgcn_mfma_f32_16x16x32_f16(ah, wh, a0, 0,0,0);
  ax = __builtin_amdgcn_mfma_f32_16x16x32_f16(al, wh, ax, 0,0,0);
  ax = __builtin_amdgcn_mfma_f32_16x16x32_f16(ah, wl, ax, 0,0,0);
}

template<int NT>
__device__ __forceinline__ void zacc(f32x4 (&a0)[4][NT], f32x4 (&ax)[4][NT]){
  f32x4 z = {0.f,0.f,0.f,0.f};
#pragma unroll
  for(int m=0;m<4;++m)
#pragma unroll
    for(int n=0;n<NT;++n){ a0[m][n]=z; ax[m][n]=z; }
}

// A frags: actF[(m*32+ks)*2+hl][512]  (hl: 0=hi,1=lo2k), lane l gets 8 u16 at l*8.
// W frags: wF  [(tile*32+ks)*2+hl][512]
template<int NT, int TS>
__device__ __forceinline__ void gemm_run(const u16* __restrict__ actF,
                                         const u16* __restrict__ wF,
                                         int tbase, int ks0, int nks, int l,
                                         f32x4 (&a0)[4][NT], f32x4 (&ax)[4][NT]){
  for(int ks = ks0; ks < ks0 + nks; ++ks){
    h8 Ah[4], Al[4];
#pragma unroll
    for(int m=0;m<4;++m){
      const u16* ab = actF + ((size_t)(m*32 + ks)*2)*512 + l*8;
      Ah[m] = *reinterpret_cast<const h8*>(ab);
      Al[m] = *reinterpret_cast<const h8*>(ab + 512);
    }
#pragma unroll
    for(int n=0;n<NT;++n){
      const u16* wb = wF + ((size_t)((tbase + n*TS)*32 + ks)*2)*512 + l*8;
      h8 Wh = *reinterpret_cast<const h8*>(wb);
      h8 Wl = *reinterpret_cast<const h8*>(wb + 512);
#pragma unroll
      for(int m=0;m<4;++m) mm3(Ah[m], Al[m], Wh, Wl, a0[m][n], ax[m][n]);
    }
  }
}

// collapse split-acc; write wave's C tile to LDS [wv][m][n+nofs][row16][col16], NTOT cols
template<int NT, int NTOT>
__device__ __forceinline__ void to_ldsN(float* lds, int wv, int l, int nofs,
                                        f32x4 (&a0)[4][NT], f32x4 (&ax)[4][NT]){
#pragma unroll
  for(int m=0;m<4;++m)
#pragma unroll
    for(int n=0;n<NT;++n)
#pragma unroll
      for(int r=0;r<4;++r){
        float v = a0[m][n][r] + ax[m][n][r]*(1.f/2048.f);
        lds[ ((((wv*4+m)*NTOT+(n+nofs))*16) + ((l>>4)*4 + r))*16 + (l&15) ] = v;
      }
}

__device__ __forceinline__ float red4(const float* lds, int nt, int m, int n, int r16, int c16){
  int base = ((m*nt + n)*16 + r16)*16 + c16;
  int strd = 4*nt*256;
  return lds[base] + lds[base+strd] + lds[base+2*strd] + lds[base+3*strd];
}

// store one activation element into a frag buffer (hi + lo2k)
__device__ __forceinline__ void store_frag(u16* __restrict__ F, int b, int c, float v){
  int m16 = b>>4, ks = c>>5, fl = (b&15) + 16*((c>>3)&3), j = c&7;
  size_t base = ((size_t)(m16*32 + ks)*2)*512 + fl*8 + j;
  _Float16 h = (_Float16)v;
  F[base]       = h2u(h);
  F[base + 512] = h2u((_Float16)((v - (float)h)*2048.f));
}

// global barrier: monotone counter (zeroed by k_bzero each launch)
__device__ __forceinline__ void gbar(u32* __restrict__ ctr, u32 target){
  __threadfence();
  __syncthreads();
  if (threadIdx.x == 0){
    __hip_atomic_fetch_add(ctr, 1u, __ATOMIC_RELAXED, __HIP_MEMORY_SCOPE_AGENT);
    while (__hip_atomic_load(ctr, __ATOMIC_RELAXED, __HIP_MEMORY_SCOPE_AGENT) < target)
      __builtin_amdgcn_s_sleep(2);
  }
  __syncthreads();
  __threadfence();
}

// ---- one-time: weight -> fragment conversion --------------------------------
__global__ __launch_bounds__(256) void k_wcvt(const float* __restrict__ W, int N, int K, int KS,
                                              u16* __restrict__ dst){
  const int f = blockIdx.x*4 + (threadIdx.x>>6);
  const int l = threadIdx.x & 63;
  const int tile = f / KS, ks = f - tile*KS;
  const int row = tile*16 + (l&15);
  const int kb  = ks*32 + (l>>4)*8;
  float v[8];
  if(row < N){
    float4 v0 = *reinterpret_cast<const float4*>(W + (size_t)row*K + kb);
    float4 v1 = *reinterpret_cast<const float4*>(W + (size_t)row*K + kb + 4);
    v[0]=v0.x; v[1]=v0.y; v[2]=v0.z; v[3]=v0.w;
    v[4]=v1.x; v[5]=v1.y; v[6]=v1.z; v[7]=v1.w;
  } else {
#pragma unroll
    for(int j=0;j<8;++j) v[j]=0.f;
  }
  h8 hi, lo; cvt8(v, hi, lo);
  *reinterpret_cast<h8*>(dst + (size_t)f*1024 + l*8)       = hi;
  *reinterpret_cast<h8*>(dst + (size_t)f*1024 + 512 + l*8) = lo;
}

// ---- init: states -> mirrors + frags, seed token ----------------------------
__global__ __launch_bounds__(256) void k_init(const float* __restrict__ efs,
                                              float* __restrict__ h0T, float* __restrict__ h1T,
                                              u16* __restrict__ h0F, u16* __restrict__ h1F,
                                              u64* __restrict__ part){
  const int idx = blockIdx.x*256 + threadIdx.x;  // 65536 = 64b x 1024k
  const int b = idx >> 10, k = idx & 1023;
  const float v0 = efs[idx];
  const float v1 = efs[65536 + idx];
  h0T[k*64 + b] = v0;
  h1T[k*64 + b] = v1;
  store_frag(h0F, b, k, v0);
  store_frag(h1F, b, k, v1);
  if(idx < 64) part[idx] = (u64)(0xFFFFFFFFu - (u32)SOS_);
}

__global__ void k_bzero(u32* __restrict__ ctr){
  if (threadIdx.x == 0) *ctr = 0u;
}

// ---- persistent: all 256 steps, 4 global barriers per step ------------------
__global__ __launch_bounds__(256, 2) void k_loop(
    const float* __restrict__ emb,
    const u16* __restrict__ wih0F, const u16* __restrict__ whh0F,
    const u16* __restrict__ whh1F, const u16* __restrict__ wih1F,
    const u16* __restrict__ pw1F,  const u16* __restrict__ pw2F,
    const float* __restrict__ bih0, const float* __restrict__ bhh0,
    const float* __restrict__ bih1, const float* __restrict__ bhh1,
    const float* __restrict__ pb1,  const float* __restrict__ pb2,
    u16* __restrict__ h0Fa, u16* __restrict__ h0Fb,
    u16* __restrict__ h1Fa, u16* __restrict__ h1Fb,
    u16* __restrict__ hidF,
    float* __restrict__ h0Ta, float* __restrict__ h0Tb,
    float* __restrict__ h1Ta, float* __restrict__ h1Tb,
    float* __restrict__ gh1T,
    float* __restrict__ out, u64* __restrict__ part, u32* __restrict__ ctr){
  __shared__ float lds[4*4*4*256];   // 64 KB
  __shared__ int tokL[64];
  const int tid = threadIdx.x, l = tid & 63, wv = tid >> 6, wg = blockIdx.x;
  u32 bno = 0;

  for (int t = 0; t < T_; ++t){
    const u16*  h0Fc = (t & 1) ? h0Fb : h0Fa;
    u16*        h0Fn = (t & 1) ? h0Fa : h0Fb;
    const u16*  h1Fc = (t & 1) ? h1Fb : h1Fa;
    u16*        h1Fn = (t & 1) ? h1Fa : h1Fb;
    const float* h0Tc = (t & 1) ? h0Tb : h0Ta;
    float*       h0Tn = (t & 1) ? h0Ta : h0Tb;
    const float* h1Tc = (t & 1) ? h1Tb : h1Ta;
    float*       h1Tn = (t & 1) ? h1Ta : h1Tb;

    // ================= phase A: GRU0 -> h0n (wg<64); gh1 (64<=wg<128) ========
    if (wg < 64){
      if(tid < 64) tokL[tid] = (int)(0xFFFFFFFFu - (u32)(part[tid] & 0xFFFFFFFFull));
      __syncthreads();
      const int tt = wg;
      f32x4 a0[4][3], ax[4][3];
      zacc<3>(a0, ax);
      // gi0 over K=512, this wave's ks chunk [wv*4, wv*4+4)
      for(int ks = wv*4; ks < wv*4+4; ++ks){
        h8 Ah[4], Al[4];
#pragma unroll
        for(int m=0;m<4;++m){
          const int b = m*16 + (l&15);
          const float* ep = emb + (size_t)tokL[b]*512 + ks*32 + (l>>4)*8;
          float4 u0 = *reinterpret_cast<const float4*>(ep);
          float4 u1 = *reinterpret_cast<const float4*>(ep + 4);
          float v[8] = { fmaxf(u0.x,0.f), fmaxf(u0.y,0.f), fmaxf(u0.z,0.f), fmaxf(u0.w,0.f),
                         fmaxf(u1.x,0.f), fmaxf(u1.y,0.f), fmaxf(u1.z,0.f), fmaxf(u1.w,0.f) };
          cvt8(v, Ah[m], Al[m]);
        }
#pragma unroll
        for(int g=0;g<3;++g){
          const u16* wb = wih0F + ((size_t)((g*64 + tt)*16 + ks)*2)*512 + l*8;
          h8 Wh = *reinterpret_cast<const h8*>(wb);
          h8 Wl = *reinterpret_cast<const h8*>(wb + 512);
#pragma unroll
          for(int m=0;m<4;++m) mm3(Ah[m], Al[m], Wh, Wl, a0[m][g], ax[m][g]);
        }
      }
      to_ldsN<3,3>(lds, wv, l, 0, a0, ax);
      __syncthreads();
      const int b = l;
      float gifin[4][3];
#pragma unroll
      for(int i=0;i<4;++i){
        const int c16 = wv + 4*i;
#pragma unroll
        for(int g=0;g<3;++g) gifin[i][g] = red4(lds, 3, b>>4, g, b&15, c16);
      }
      __syncthreads();
      // gh0 over K=1024, chunk [wv*8, wv*8+8)
      zacc<3>(a0, ax);
      gemm_run<3,64>(h0Fc, whh0F, tt, wv*8, 8, l, a0, ax);
      to_ldsN<3,3>(lds, wv, l, 0, a0, ax);
      __syncthreads();
#pragma unroll
      for(int i=0;i<4;++i){
        const int c16 = wv + 4*i;
        const int c = tt*16 + c16;
        const float hr = red4(lds, 3, b>>4, 0, b&15, c16) + bhh0[c];
        const float hz = red4(lds, 3, b>>4, 1, b&15, c16) + bhh0[1024+c];
        const float hn = red4(lds, 3, b>>4, 2, b&15, c16) + bhh0[2048+c];
        const float ir = gifin[i][0] + bih0[c];
        const float iz = gifin[i][1] + bih0[1024+c];
        const float in_ = gifin[i][2] + bih0[2048+c];
        const float r = sig_(ir+hr), z = sig_(iz+hz);
        const float n = tanhf(in_ + r*hn);
        const float ho = h0Tc[c*64 + b];
        const float hv = (1.f-z)*n + z*ho;
        h0Tn[c*64 + b] = hv;
        store_frag(h0Fn, b, c, hv);
      }
    } else if (wg < 128){
      const int tt = wg - 64;
      f32x4 a0[4][3], ax[4][3];
      zacc<3>(a0, ax);
      gemm_run<3,64>(h1Fc, whh1F, tt, wv*8, 8, l, a0, ax);
      to_ldsN<3,3>(lds, wv, l, 0, a0, ax);
      __syncthreads();
      const int b = l;
#pragma unroll
      for(int i=0;i<4;++i){
        const int c16 = wv + 4*i;
        const int c = tt*16 + c16;
#pragma unroll
        for(int g=0;g<3;++g){
          const float v = red4(lds, 3, b>>4, g, b&15, c16) + bhh1[g*1024 + c];
          gh1T[(size_t)(g*1024 + c)*64 + b] = v;
        }
      }
    }
    gbar(ctr, 256u*(++bno));

    // ================= phase B: gi1 + combine -> h1n (wg<64) =================
    if (wg < 64){
      const int tt = wg;
      f32x4 a0[4][3], ax[4][3];
      zacc<3>(a0, ax);
      gemm_run<3,64>(h0Fn, wih1F, tt, wv*8, 8, l, a0, ax);
      to_ldsN<3,3>(lds, wv, l, 0, a0, ax);
      __syncthreads();
      const int b = l;
#pragma unroll
      for(int i=0;i<4;++i){
        const int c16 = wv + 4*i;
        const int c = tt*16 + c16;
        const float ir = red4(lds, 3, b>>4, 0, b&15, c16) + bih1[c];
        const float iz = red4(lds, 3, b>>4, 1, b&15, c16) + bih1[1024+c];
        const float in_ = red4(lds, 3, b>>4, 2, b&15, c16) + bih1[2048+c];
        const float hr = gh1T[(size_t)(0*1024 + c)*64 + b];
        const float hz = gh1T[(size_t)(1*1024 + c)*64 + b];
        const float hn = gh1T[(size_t)(2*1024 + c)*64 + b];
        const float r = sig_(ir+hr), z = sig_(iz+hz);
        const float n = tanhf(in_ + r*hn);
        const float ho = h1Tc[c*64 + b];
        const float hv = (1.f-z)*n + z*ho;
        h1Tn[c*64 + b] = hv;
        store_frag(h1Fn, b, c, hv);
      }
    }
    gbar(ctr, 256u*(++bno));

    // ================= phase C: hid = relu(FC1) (wg<16); part reset (wg 255) =
    if (wg < 16){
      const int tt = wg;
      f32x4 a0[4][2], ax[4][2];
      zacc<2>(a0, ax);
      gemm_run<2,1>(h1Fn, pw1F, tt*4, wv*8, 8, l, a0, ax);
      to_ldsN<2,4>(lds, wv, l, 0, a0, ax);
      zacc<2>(a0, ax);
      gemm_run<2,1>(h1Fn, pw1F, tt*4+2, wv*8, 8, l, a0, ax);
      to_ldsN<2,4>(lds, wv, l, 2, a0, ax);
      __syncthreads();
      const int b = l;
#pragma unroll
      for(int i=0;i<16;++i){
        const int col = wv + 4*i;
        const int c = tt*64 + col;
        const float v = red4(lds, 4, b>>4, col>>4, b&15, col&15) + pb1[c];
        store_frag(hidF, b, c, fmaxf(v, 0.f));
      }
    }
    if (wg == 255 && tid < 64) part[tid] = 0ull;
    gbar(ctr, 256u*(++bno));

    // ================= phase D: logits + argmax (wg<157) =====================
    if (wg < 157){
      const int v0 = wg;
      const int c0 = v0*64;
      f32x4 a0[4][2], ax[4][2];
      zacc<2>(a0, ax);
      gemm_run<2,1>(hidF, pw2F, v0*4, wv*8, 8, l, a0, ax);
      to_ldsN<2,4>(lds, wv, l, 0, a0, ax);
      zacc<2>(a0, ax);
      gemm_run<2,1>(hidF, pw2F, v0*4+2, wv*8, 8, l, a0, ax);
      to_ldsN<2,4>(lds, wv, l, 2, a0, ax);
      __syncthreads();
#pragma unroll
      for(int i=0;i<16;++i){
        const int row = wv + 4*i;           // batch
        const int col = l;
        const int c = c0 + col;
        float s = red4(lds, 4, row>>4, col>>4, row&15, col&15);
        u64 p = 0ull;
        if(c < V_){
          s += pb2[c];
          out[((size_t)row*T_ + t)*V_ + c] = s;
          u32 kb = __float_as_uint(s);
          kb = (kb & 0x80000000u) ? ~kb : (kb | 0x80000000u);
          p = ((u64)kb << 32) | (u64)(0xFFFFFFFFu - (u32)c);
        }
#pragma unroll
        for(int d=1; d<64; d<<=1){
          const u64 o = __shfl_xor(p, d, 64);
          if(o > p) p = o;
        }
        if(l == 0) atomicMax(&part[row], p);
      }
      __syncthreads();
    }
    gbar(ctr, 256u*(++bno));
  }
}

extern "C" void kernel_launch(void* const* d_in, const int* in_sizes, int n_in,
                              void* d_out, int out_size, void* d_ws, size_t ws_size,
                              hipStream_t stream) {
  (void)in_sizes; (void)n_in; (void)out_size;
  const float* efs  = (const float*)d_in[1];
  const float* embW = (const float*)d_in[2];
  const float* Wih0 = (const float*)d_in[3];
  const float* Whh0 = (const float*)d_in[4];
  const float* bih0 = (const float*)d_in[5];
  const float* bhh0 = (const float*)d_in[6];
  const float* Wih1 = (const float*)d_in[7];
  const float* Whh1 = (const float*)d_in[8];
  const float* bih1 = (const float*)d_in[9];
  const float* bhh1 = (const float*)d_in[10];
  const float* pW1  = (const float*)d_in[11];
  const float* pb1  = (const float*)d_in[12];
  const float* pW2  = (const float*)d_in[13];
  const float* pb2  = (const float*)d_in[14];
  float* out = (float*)d_out;

  // ws layout (bytes)
  const size_t o_wih0F = 0;          // 192t x 16ks x 2KB = 6,291,456
  const size_t o_whh0F = 6291456;    // 192 x 32 = 12,582,912
  const size_t o_whh1F = 18874368;
  const size_t o_wih1F = 31457280;
  const size_t o_pw1F  = 44040192;   // 64 x 32 = 4,194,304
  const size_t o_pw2F  = 48234496;   // 628 x 32 = 41,156,608
  const size_t o_h0Fa  = 89391104;   // act frag buffers: 262,144 each
  const size_t o_h0Fb  = 89653248;
  const size_t o_h1Fa  = 89915392;
  const size_t o_h1Fb  = 90177536;
  const size_t o_hidF  = 90439680;
  const size_t o_h0Ta  = 90701824;   // f32 mirrors [c][b]: 262,144 each
  const size_t o_h0Tb  = 90963968;
  const size_t o_h1Ta  = 91226112;
  const size_t o_h1Tb  = 91488256;
  const size_t o_gh1T  = 91750400;   // 786,432
  const size_t o_part  = 92536832;   // 512
  const size_t o_ctr   = 92537344;   // 512
  const size_t need    = 92537856;
  if(ws_size < need) return;         // loud zero-output failure (diagnostic)

  char* ws = (char*)d_ws;
  u16* wih0F = (u16*)(ws + o_wih0F);
  u16* whh0F = (u16*)(ws + o_whh0F);
  u16* whh1F = (u16*)(ws + o_whh1F);
  u16* wih1F = (u16*)(ws + o_wih1F);
  u16* pw1F  = (u16*)(ws + o_pw1F);
  u16* pw2F  = (u16*)(ws + o_pw2F);
  u16* h0Fa  = (u16*)(ws + o_h0Fa);
  u16* h0Fb  = (u16*)(ws + o_h0Fb);
  u16* h1Fa  = (u16*)(ws + o_h1Fa);
  u16* h1Fb  = (u16*)(ws + o_h1Fb);
  u16* hidF  = (u16*)(ws + o_hidF);
  float* h0Ta = (float*)(ws + o_h0Ta);
  float* h0Tb = (float*)(ws + o_h0Tb);
  float* h1Ta = (float*)(ws + o_h1Ta);
  float* h1Tb = (float*)(ws + o_h1Tb);
  float* gh1T = (float*)(ws + o_gh1T);
  u64*   part = (u64*)(ws + o_part);
  u32*   ctr  = (u32*)(ws + o_ctr);

  // one-time per launch: weight fragment conversion + state init + barrier reset
  k_wcvt<<<dim3(768),  dim3(256), 0, stream>>>(Wih0, 3072, 512, 16, wih0F);
  k_wcvt<<<dim3(1536), dim3(256), 0, stream>>>(Whh0, 3072, 1024, 32, whh0F);
  k_wcvt<<<dim3(1536), dim3(256), 0, stream>>>(Whh1, 3072, 1024, 32, whh1F);
  k_wcvt<<<dim3(1536), dim3(256), 0, stream>>>(Wih1, 3072, 1024, 32, wih1F);
  k_wcvt<<<dim3(512),  dim3(256), 0, stream>>>(pW1, 1024, 1024, 32, pw1F);
  k_wcvt<<<dim3(5024), dim3(256), 0, stream>>>(pW2, V_, 1024, 32, pw2F);
  k_init<<<dim3(256),  dim3(256), 0, stream>>>(efs, h0Ta, h1Ta, h0Fa, h1Fa, part);
  k_bzero<<<dim3(1),   dim3(64),  0, stream>>>(ctr);

  // persistent step loop: 256 WGs (<= half of guaranteed co-residency capacity)
  k_loop<<<dim3(256), dim3(256), 0, stream>>>(
      embW, wih0F, whh0F, whh1F, wih1F, pw1F, pw2F,
      bih0, bhh0, bih1, bhh1, pb1, pb2,
      h0Fa, h0Fb, h1Fa, h1Fb, hidF,
      h0Ta, h0Tb, h1Ta, h1Tb, gh1T,
      out, part, ctr);
}